// Round 5
// baseline (788.306 us; speedup 1.0000x reference)
//
#include <hip/hip_runtime.h>
#include <hip/hip_bf16.h>

#define B_ 8
#define C_ 64
#define N_ 4096
#define K_ 20
#define O_ 64

constexpr float BN_EPS = 1e-5f;
constexpr float NEG = 0.2f;
constexpr int ROWS = B_ * N_;        // 32768
constexpr int M_TOT = ROWS * K_;     // 655360
constexpr int RT = 8;                // q rows per wave in knn
constexpr int JT = 128;              // j-tile per block in knn

__device__ __forceinline__ float readlane_f(float v, int src) {
  return __int_as_float(__builtin_amdgcn_readlane(__float_as_int(v), src));
}

// ----------------------------------------------------------------------------
// ws layout (float elements):
//   y   : [0,        2097152)   y[b][n][o]  = xt[b,n,:]  . W1[o,:]
//   z   : [2097152,  4194304)   z[b][n][o]  = xt[b,n,:]  . (W2-W1)[o,:]
//   xx  : [4194304,  4227072)   xx[b][n]    = ||xt[b,n,:]||^2
//   idx : [4227072,  4882432)   (int) idx[b][n][k]
//   s1/s2/sc/sh : 64 floats each after that
// ----------------------------------------------------------------------------

__global__ __launch_bounds__(256) void prep_kernel(const float* __restrict__ x,
                                                   const float* __restrict__ W,
                                                   float* __restrict__ y,
                                                   float* __restrict__ z,
                                                   float* __restrict__ xx) {
  __shared__ float xt[64][65];  // [n_local][c]
  __shared__ float w1[64][65];  // [o][c]   = W[o][c]
  __shared__ float wd[64][65];  // [o][c]   = W[o][64+c] - W[o][c]
  const int b = blockIdx.x >> 6;
  const int n0 = (blockIdx.x & 63) << 6;
  const int tid = threadIdx.x;

  for (int rep = 0; rep < 16; ++rep) {
    int id = rep * 256 + tid;
    int cc = id >> 6, nl = id & 63;
    xt[nl][cc] = x[((b * 64 + cc) << 12) + n0 + nl];  // coalesced over nl
    int o = cc, c = nl;
    float a = W[o * 128 + c];
    float bb = W[o * 128 + 64 + c];
    w1[o][c] = a;
    wd[o][c] = bb - a;
  }
  __syncthreads();

  const int o = tid & 63;
  for (int nl = tid >> 6; nl < 64; nl += 4) {
    float ay = 0.f, az = 0.f;
#pragma unroll 8
    for (int c = 0; c < 64; ++c) {
      float v = xt[nl][c];
      ay = fmaf(v, w1[o][c], ay);
      az = fmaf(v, wd[o][c], az);
    }
    int gi = (((b << 12) + n0 + nl) << 6) + o;
    y[gi] = ay;
    z[gi] = az;
  }
  if (tid < 64) {
    float s = 0.f;
#pragma unroll 8
    for (int c = 0; c < 64; ++c) {
      float v = xt[tid][c];
      s = fmaf(v, v, s);
    }
    xx[(b << 12) + n0 + tid] = s;
  }
}

// knn v5: GEMM-shaped. Block = 4 waves x 8 q-rows = 32 q-rows; each 128-j
// tile of x is staged into LDS once per block (shared by 4 waves -> 4x less
// global traffic, and the inner loop reads xj from LDS instead of 16KB-strided
// global = the latency sink of v2-v4). xq via wave-uniform s_load (SGPR
// operand). Per-(q,j) fmaf chain is ascending-c, identical to v2-v4 ->
// identical neighbor sets.
__global__ __launch_bounds__(256, 4) void knn_kernel(const float* __restrict__ x,
                                                     const float* __restrict__ xx,
                                                     int* __restrict__ idx) {
  const int tid = threadIdx.x;
  const int w = tid >> 6;              // wave 0..3
  const int lane = tid & 63;
  const int row0 = blockIdx.x * 32;    // 32 q rows per block, same batch
  const int b = row0 >> 12;
  const int i0 = row0 & 4095;
  const float* xb = x + ((size_t)b << 18);   // b*64*4096
  const float* xxb = xx + (b << 12);
  const float* xqp = xb + i0 + 8 * w;        // wave's rows: xqp[c*4096 + r]

  __shared__ float lds_j[64 * JT];           // [c][j], 32 KB

  float bv[RT], T[RT];
  int bi[RT];
#pragma unroll
  for (int r = 0; r < RT; ++r) {
    bv[r] = __builtin_inff();
    T[r] = __builtin_inff();
    bi[r] = 0;
  }

  const int jf = tid & 31;   // float4 index within a c-row (0..31)
  const int c0 = tid >> 5;   // 0..7

  for (int jb = 0; jb < N_; jb += JT) {
    // ---- stage 64 x 128 j-tile into LDS (coalesced) ----
#pragma unroll
    for (int i = 0; i < 8; ++i) {
      int c = c0 + i * 8;
      float4 v = *(const float4*)(xb + ((size_t)c << 12) + jb + (jf << 2));
      *(float4*)&lds_j[c * JT + (jf << 2)] = v;
    }
    __syncthreads();

    // ---- compute: each lane handles 2 j's x 8 q-rows ----
    float2 acc[RT];
#pragma unroll
    for (int r = 0; r < RT; ++r) acc[r] = make_float2(0.f, 0.f);
    const float* ljp = &lds_j[lane << 1];
#pragma unroll 8
    for (int c = 0; c < 64; ++c) {
      float2 xj = *(const float2*)(ljp + c * JT);
#pragma unroll
      for (int r = 0; r < RT; ++r) {
        float xic = xqp[((size_t)c << 12) + r];  // wave-uniform -> s_load
        acc[r].x = fmaf(xic, xj.x, acc[r].x);
        acc[r].y = fmaf(xic, xj.y, acc[r].y);
      }
    }

    // ---- selection (identical insert logic to v4) ----
    const int j0 = jb + (lane << 1);
    float2 xxj = *(const float2*)(xxb + j0);
#pragma unroll
    for (int r = 0; r < RT; ++r) {
      float dv[2] = {xxj.x - 2.f * acc[r].x, xxj.y - 2.f * acc[r].y};
#pragma unroll
      for (int jj = 0; jj < 2; ++jj) {
        float v = dv[jj];
        unsigned long long m = __ballot(v < T[r]);
        while (m) {
          int src = __ffsll(m) - 1;
          m &= m - 1;
          float cv = readlane_f(v, src);               // VALU, not DS
          int cj = __builtin_amdgcn_readlane(j0 + jj, src);
          if (cv < T[r]) {  // T may have shrunk since the ballot
            unsigned long long le = __ballot(bv[r] <= cv) & 0xFFFFFull;
            int pos = __popcll(le);
            float pv = __shfl_up(bv[r], 1);            // DS (x2 total)
            int pi = __shfl_up(bi[r], 1);
            if (lane >= pos) {
              bool ins = (lane == pos);
              bv[r] = ins ? cv : pv;
              bi[r] = ins ? cj : pi;
            }
            T[r] = readlane_f(bv[r], K_ - 1);          // VALU, not DS
          }
        }
      }
    }
    __syncthreads();  // before next tile overwrites lds_j
  }

#pragma unroll
  for (int r = 0; r < RT; ++r) {
    if (lane < K_) idx[(row0 + 8 * w + r) * K_ + lane] = bi[r];
  }
}

__global__ __launch_bounds__(256) void stats_kernel(const float* __restrict__ y,
                                                    const float* __restrict__ z,
                                                    const int* __restrict__ idx,
                                                    float* __restrict__ s1,
                                                    float* __restrict__ s2) {
  const int tid = threadIdx.x;
  const int o = tid & 63;
  const int r = tid >> 6;
  const int row0 = blockIdx.x << 6;  // 64 rows per block
  float a1 = 0.f, a2 = 0.f;
  for (int rl = r; rl < 64; rl += 4) {
    const int row = row0 + rl;
    const int b = row >> 12;
    const float zv = z[(row << 6) + o];
    const int* ip = idx + row * K_;
    const float* yb = y + ((size_t)b << 18);
    float s1r = 0.f;
#pragma unroll
    for (int k = 0; k < K_; ++k) {
      int j = ip[k];
      float h = yb[(j << 6) + o] + zv;
      s1r += h;
      a2 = fmaf(h, h, a2);
    }
    a1 += s1r;
  }
  __shared__ float r1[4][64];
  __shared__ float r2[4][64];
  r1[r][o] = a1;
  r2[r][o] = a2;
  __syncthreads();
  if (tid < 64) {
    float t1 = r1[0][tid] + r1[1][tid] + r1[2][tid] + r1[3][tid];
    float t2 = r2[0][tid] + r2[1][tid] + r2[2][tid] + r2[3][tid];
    atomicAdd(&s1[tid], t1);
    atomicAdd(&s2[tid], t2);
  }
}

__global__ void finalize_kernel(const float* __restrict__ s1,
                                const float* __restrict__ s2,
                                const float* __restrict__ gamma,
                                const float* __restrict__ beta,
                                float* __restrict__ sc,
                                float* __restrict__ sh) {
  int o = threadIdx.x;
  float mean = s1[o] / (float)M_TOT;
  float var = s2[o] / (float)M_TOT - mean * mean;
  float inv = 1.0f / sqrtf(var + BN_EPS);
  float s = gamma[o] * inv;
  sc[o] = s;
  sh[o] = beta[o] - mean * s;
}

__global__ __launch_bounds__(256) void out_kernel(const float* __restrict__ y,
                                                  const float* __restrict__ z,
                                                  const int* __restrict__ idx,
                                                  const float* __restrict__ sc,
                                                  const float* __restrict__ sh,
                                                  float* __restrict__ out) {
  __shared__ float til[64][65];  // [o][n_local]
  const int tid = threadIdx.x;
  const int b = blockIdx.x >> 6;
  const int n0 = (blockIdx.x & 63) << 6;
  const int o = tid & 63;
  const float s = sc[o];
  const float t = sh[o];
  const float* yb = y + ((size_t)b << 18);

  for (int nl = tid >> 6; nl < 64; nl += 4) {
    const int row = (b << 12) + n0 + nl;
    const float zv = z[(row << 6) + o];
    const int* ip = idx + row * K_;
    float m = -__builtin_inff();
#pragma unroll
    for (int k = 0; k < K_; ++k) {
      int j = ip[k];
      float h = yb[(j << 6) + o] + zv;
      float hn = fmaf(h, s, t);
      float a = hn >= 0.f ? hn : NEG * hn;
      m = fmaxf(m, a);
    }
    til[o][nl] = m;
  }
  __syncthreads();
  for (int rep = 0; rep < 16; ++rep) {
    int id = rep * 256 + tid;
    int oo = id >> 6, nl = id & 63;
    out[((size_t)((b << 6) + oo) << 12) + n0 + nl] = til[oo][nl];
  }
}

extern "C" void kernel_launch(void* const* d_in, const int* in_sizes, int n_in,
                              void* d_out, int out_size, void* d_ws, size_t ws_size,
                              hipStream_t stream) {
  const float* x = (const float*)d_in[0];
  const float* W = (const float*)d_in[1];
  const float* gamma = (const float*)d_in[2];
  const float* beta = (const float*)d_in[3];
  float* ws = (float*)d_ws;
  float* y = ws;
  float* z = ws + 2097152;
  float* xx = ws + 4194304;
  int* idxp = (int*)(ws + 4227072);
  float* s1 = ws + 4882432;
  float* s2 = ws + 4882496;
  float* sc = ws + 4882560;
  float* sh = ws + 4882624;
  float* out = (float*)d_out;

  hipMemsetAsync(s1, 0, 2 * 64 * sizeof(float), stream);

  prep_kernel<<<512, 256, 0, stream>>>(x, W, y, z, xx);
  knn_kernel<<<ROWS / 32, 256, 0, stream>>>(x, xx, idxp);
  stats_kernel<<<512, 256, 0, stream>>>(y, z, idxp, s1, s2);
  finalize_kernel<<<1, 64, 0, stream>>>(s1, s2, gamma, beta, sc, sh);
  out_kernel<<<512, 256, 0, stream>>>(y, z, idxp, sc, sh, out);
}

// Round 6
// 634.893 us; speedup vs baseline: 1.2416x; 1.2416x over previous
//
#include <hip/hip_runtime.h>
#include <hip/hip_bf16.h>

#define B_ 8
#define C_ 64
#define N_ 4096
#define K_ 20
#define O_ 64

constexpr float BN_EPS = 1e-5f;
constexpr float NEG = 0.2f;
constexpr int ROWS = B_ * N_;        // 32768
constexpr int M_TOT = ROWS * K_;     // 655360
constexpr int RT = 4;                // q rows per wave in knn

__device__ __forceinline__ float readlane_f(float v, int src) {
  return __int_as_float(__builtin_amdgcn_readlane(__float_as_int(v), src));
}

// ----------------------------------------------------------------------------
// ws layout (float elements):
//   y   : [0,        2097152)   y[b][n][o]  = xt[b,n,:]  . W1[o,:]
//   z   : [2097152,  4194304)   z[b][n][o]  = xt[b,n,:]  . (W2-W1)[o,:]
//   xx  : [4194304,  4227072)   xx[b][n]    = ||xt[b,n,:]||^2
//   idx : [4227072,  4882432)   (int) idx[b][n][k]
//   s1/s2/sc/sh : 64 floats each after that
// ----------------------------------------------------------------------------

__global__ __launch_bounds__(256) void prep_kernel(const float* __restrict__ x,
                                                   const float* __restrict__ W,
                                                   float* __restrict__ y,
                                                   float* __restrict__ z,
                                                   float* __restrict__ xx) {
  __shared__ float xt[64][65];  // [n_local][c]
  __shared__ float w1[64][65];  // [o][c]   = W[o][c]
  __shared__ float wd[64][65];  // [o][c]   = W[o][64+c] - W[o][c]
  const int b = blockIdx.x >> 6;
  const int n0 = (blockIdx.x & 63) << 6;
  const int tid = threadIdx.x;

  for (int rep = 0; rep < 16; ++rep) {
    int id = rep * 256 + tid;
    int cc = id >> 6, nl = id & 63;
    xt[nl][cc] = x[((b * 64 + cc) << 12) + n0 + nl];  // coalesced over nl
    int o = cc, c = nl;
    float a = W[o * 128 + c];
    float bb = W[o * 128 + 64 + c];
    w1[o][c] = a;
    wd[o][c] = bb - a;
  }
  __syncthreads();

  const int o = tid & 63;
  for (int nl = tid >> 6; nl < 64; nl += 4) {
    float ay = 0.f, az = 0.f;
#pragma unroll 8
    for (int c = 0; c < 64; ++c) {
      float v = xt[nl][c];
      ay = fmaf(v, w1[o][c], ay);
      az = fmaf(v, wd[o][c], az);
    }
    int gi = (((b << 12) + n0 + nl) << 6) + o;
    y[gi] = ay;
    z[gi] = az;
  }
  if (tid < 64) {
    float s = 0.f;
#pragma unroll 8
    for (int c = 0; c < 64; ++c) {
      float v = xt[tid][c];
      s = fmaf(v, v, s);
    }
    xx[(b << 12) + n0 + tid] = s;
  }
}

// knn v6: occupancy-first. RT=4 -> 8192 waves = 8 waves/SIMD (grid was the
// occupancy limiter in v2-v5). xi via LDS broadcast (one ds_read_b128 per c).
// Fresh-ballot selection: re-ballot against the updated threshold each
// iteration (+ processed-lane mask) -> serialized iterations = true inserts
// only (~106/row), no stale-candidate recheck.
// Per-(i,j) fmaf chain is ascending-c, identical to v2-v5 -> identical
// neighbor sets.
__global__ __launch_bounds__(256, 8) void knn_kernel(const float* __restrict__ x,
                                                     const float* __restrict__ xx,
                                                     int* __restrict__ idx) {
  const int tid = threadIdx.x;
  const int w = tid >> 6;              // wave 0..3
  const int lane = tid & 63;
  const int row0 = blockIdx.x * 16 + 4 * w;  // this wave's 4 rows
  const int b = row0 >> 12;
  const int i0 = row0 & 4095;
  const float* xb = x + ((size_t)b << 18);   // b*64*4096
  const float* xxb = xx + (b << 12);

  __shared__ float4 xi4[4][64];        // [wave][c] = xq rows 0..3 at channel c

  // one-time staging: lane c loads this wave's 4 consecutive rows at channel c
  xi4[w][lane] = *(const float4*)(xb + ((size_t)lane << 12) + i0);
  // written and read by the same wave only -> no barrier needed

  float bv[RT], T[RT];
  int bi[RT];
#pragma unroll
  for (int r = 0; r < RT; ++r) {
    bv[r] = __builtin_inff();
    T[r] = __builtin_inff();
    bi[r] = 0;
  }

  for (int jb = 0; jb < N_; jb += 256) {
    const int j0 = jb + (lane << 2);
    float4 acc[RT];
#pragma unroll
    for (int r = 0; r < RT; ++r) acc[r] = make_float4(0.f, 0.f, 0.f, 0.f);
    const float* xp = xb + j0;
#pragma unroll 4
    for (int c = 0; c < 64; ++c) {
      float4 xj = *(const float4*)(xp + ((size_t)c << 12));
      float4 xa = xi4[w][c];           // same-addr wave broadcast (1 b128)
      acc[0].x = fmaf(xa.x, xj.x, acc[0].x);
      acc[0].y = fmaf(xa.x, xj.y, acc[0].y);
      acc[0].z = fmaf(xa.x, xj.z, acc[0].z);
      acc[0].w = fmaf(xa.x, xj.w, acc[0].w);
      acc[1].x = fmaf(xa.y, xj.x, acc[1].x);
      acc[1].y = fmaf(xa.y, xj.y, acc[1].y);
      acc[1].z = fmaf(xa.y, xj.z, acc[1].z);
      acc[1].w = fmaf(xa.y, xj.w, acc[1].w);
      acc[2].x = fmaf(xa.z, xj.x, acc[2].x);
      acc[2].y = fmaf(xa.z, xj.y, acc[2].y);
      acc[2].z = fmaf(xa.z, xj.z, acc[2].z);
      acc[2].w = fmaf(xa.z, xj.w, acc[2].w);
      acc[3].x = fmaf(xa.w, xj.x, acc[3].x);
      acc[3].y = fmaf(xa.w, xj.y, acc[3].y);
      acc[3].z = fmaf(xa.w, xj.z, acc[3].z);
      acc[3].w = fmaf(xa.w, xj.w, acc[3].w);
    }
    float4 xxj = *(const float4*)(xxb + j0);
#pragma unroll
    for (int r = 0; r < RT; ++r) {
      float dv[4] = {xxj.x - 2.f * acc[r].x, xxj.y - 2.f * acc[r].y,
                     xxj.z - 2.f * acc[r].z, xxj.w - 2.f * acc[r].w};
#pragma unroll
      for (int jj = 0; jj < 4; ++jj) {
        float v = dv[jj];
        unsigned long long rem = 0xFFFFFFFFFFFFFFFFull;
        while (true) {
          unsigned long long m = __ballot(v < T[r]) & rem;
          if (!m) break;
          int src = __ffsll(m) - 1;
          rem &= ~(1ull << src);
          float cv = readlane_f(v, src);               // VALU broadcast
          int cj = __builtin_amdgcn_readlane(j0 + jj, src);
          // fresh ballot guarantees cv < T -> unconditional insert
          unsigned long long le = __ballot(bv[r] <= cv) & 0xFFFFFull;
          int pos = __popcll(le);
          float pv = __shfl_up(bv[r], 1);
          int pi = __shfl_up(bi[r], 1);
          if (lane >= pos) {
            bool ins = (lane == pos);
            bv[r] = ins ? cv : pv;
            bi[r] = ins ? cj : pi;
          }
          T[r] = readlane_f(bv[r], K_ - 1);
        }
      }
    }
  }

#pragma unroll
  for (int r = 0; r < RT; ++r) {
    if (lane < K_) idx[(row0 + r) * K_ + lane] = bi[r];
  }
}

__global__ __launch_bounds__(256) void stats_kernel(const float* __restrict__ y,
                                                    const float* __restrict__ z,
                                                    const int* __restrict__ idx,
                                                    float* __restrict__ s1,
                                                    float* __restrict__ s2) {
  const int tid = threadIdx.x;
  const int o = tid & 63;
  const int r = tid >> 6;
  const int row0 = blockIdx.x << 6;  // 64 rows per block
  float a1 = 0.f, a2 = 0.f;
  for (int rl = r; rl < 64; rl += 4) {
    const int row = row0 + rl;
    const int b = row >> 12;
    const float zv = z[(row << 6) + o];
    const int* ip = idx + row * K_;
    const float* yb = y + ((size_t)b << 18);
    float s1r = 0.f;
#pragma unroll
    for (int k = 0; k < K_; ++k) {
      int j = ip[k];
      float h = yb[(j << 6) + o] + zv;
      s1r += h;
      a2 = fmaf(h, h, a2);
    }
    a1 += s1r;
  }
  __shared__ float r1[4][64];
  __shared__ float r2[4][64];
  r1[r][o] = a1;
  r2[r][o] = a2;
  __syncthreads();
  if (tid < 64) {
    float t1 = r1[0][tid] + r1[1][tid] + r1[2][tid] + r1[3][tid];
    float t2 = r2[0][tid] + r2[1][tid] + r2[2][tid] + r2[3][tid];
    atomicAdd(&s1[tid], t1);
    atomicAdd(&s2[tid], t2);
  }
}

__global__ void finalize_kernel(const float* __restrict__ s1,
                                const float* __restrict__ s2,
                                const float* __restrict__ gamma,
                                const float* __restrict__ beta,
                                float* __restrict__ sc,
                                float* __restrict__ sh) {
  int o = threadIdx.x;
  float mean = s1[o] / (float)M_TOT;
  float var = s2[o] / (float)M_TOT - mean * mean;
  float inv = 1.0f / sqrtf(var + BN_EPS);
  float s = gamma[o] * inv;
  sc[o] = s;
  sh[o] = beta[o] - mean * s;
}

__global__ __launch_bounds__(256) void out_kernel(const float* __restrict__ y,
                                                  const float* __restrict__ z,
                                                  const int* __restrict__ idx,
                                                  const float* __restrict__ sc,
                                                  const float* __restrict__ sh,
                                                  float* __restrict__ out) {
  __shared__ float til[64][65];  // [o][n_local]
  const int tid = threadIdx.x;
  const int b = blockIdx.x >> 6;
  const int n0 = (blockIdx.x & 63) << 6;
  const int o = tid & 63;
  const float s = sc[o];
  const float t = sh[o];
  const float* yb = y + ((size_t)b << 18);

  for (int nl = tid >> 6; nl < 64; nl += 4) {
    const int row = (b << 12) + n0 + nl;
    const float zv = z[(row << 6) + o];
    const int* ip = idx + row * K_;
    float m = -__builtin_inff();
#pragma unroll
    for (int k = 0; k < K_; ++k) {
      int j = ip[k];
      float h = yb[(j << 6) + o] + zv;
      float hn = fmaf(h, s, t);
      float a = hn >= 0.f ? hn : NEG * hn;
      m = fmaxf(m, a);
    }
    til[o][nl] = m;
  }
  __syncthreads();
  for (int rep = 0; rep < 16; ++rep) {
    int id = rep * 256 + tid;
    int oo = id >> 6, nl = id & 63;
    out[((size_t)((b << 6) + oo) << 12) + n0 + nl] = til[oo][nl];
  }
}

extern "C" void kernel_launch(void* const* d_in, const int* in_sizes, int n_in,
                              void* d_out, int out_size, void* d_ws, size_t ws_size,
                              hipStream_t stream) {
  const float* x = (const float*)d_in[0];
  const float* W = (const float*)d_in[1];
  const float* gamma = (const float*)d_in[2];
  const float* beta = (const float*)d_in[3];
  float* ws = (float*)d_ws;
  float* y = ws;
  float* z = ws + 2097152;
  float* xx = ws + 4194304;
  int* idxp = (int*)(ws + 4227072);
  float* s1 = ws + 4882432;
  float* s2 = ws + 4882496;
  float* sc = ws + 4882560;
  float* sh = ws + 4882624;
  float* out = (float*)d_out;

  hipMemsetAsync(s1, 0, 2 * 64 * sizeof(float), stream);

  prep_kernel<<<512, 256, 0, stream>>>(x, W, y, z, xx);
  knn_kernel<<<ROWS / 16, 256, 0, stream>>>(x, xx, idxp);
  stats_kernel<<<512, 256, 0, stream>>>(y, z, idxp, s1, s2);
  finalize_kernel<<<1, 64, 0, stream>>>(s1, s2, gamma, beta, sc, sh);
  out_kernel<<<512, 256, 0, stream>>>(y, z, idxp, sc, sh, out);
}